// Round 12
// baseline (208.941 us; speedup 1.0000x reference)
//
#include <hip/hip_runtime.h>
#include <hip/hip_fp16.h>
#include <math.h>

#define B_ 128
#define C_ 10
#define R_ 8192
#define I_ 8
#define O_ 16

typedef __attribute__((ext_vector_type(8))) _Float16 half8;
typedef __attribute__((ext_vector_type(16))) float f32x16;

#define XROW 512           // uints per x r-row: 128 b * 4
#define WROW 64            // uints per W row: 16 o * 4
#define WZERO 80           // zero-row index (block-diagonal A trick)
#define SBO (C_ * B_ * O_) // 20480
#define SLOTS 512          // part slots (one per block, 16 r-rows each)

__device__ __forceinline__ unsigned pk2(float a, float b) {
    __half2 h = __floats2half2_rn(a, b);
    return *(unsigned*)&h;
}

// lane <-> lane^32 exchange as VALU (not ds_bpermute's ~120cy LDS round-trip).
// r11 FAILED: v_permlane32_swap's {r[0],r[1]} = {own,partner} but WHICH index
// is the partner depends on the swap direction (I guessed wrong). Direction-
// independent recovery: partner = r[0] ^ r[1] ^ own (uint XOR -- exact, since
// the pair is bitwise {own, partner} in either direction). 2 extra v_xor per
// swap, still pure VALU.
#if __has_builtin(__builtin_amdgcn_permlane32_swap)
__device__ __forceinline__ float xswap32(float v) {
    const unsigned own = __float_as_uint(v);
    auto r = __builtin_amdgcn_permlane32_swap(own, own, false, false);
    return __uint_as_float(r[0] ^ r[1] ^ own);
}
#else
__device__ __forceinline__ float xswap32(float v) { return __shfl_xor(v, 32); }
#endif

// ---------------------------------------------------------------------------
// fused_iter: one routing iteration. grid 512, block 512 (8 waves), TR=16.
// Structure from r9/r10 (in-block LDS reduction, part = 21 MB, zero16 C-op).
// r12: the r11 permlane change, correctness-fixed via XOR-combine (above).
// Removes ~120 chained LDS round-trips per wave from the softmax dep chain.
// NOTE (ledger): "mode0 == mode1 duration" from r3-r8 was a top-5 filtering
// artifact (slowest rows are always the 2x mode-1 per rep).
// Spill tripwire: WRITE_SIZE must stay 20480 KB exactly.
// ---------------------------------------------------------------------------
__global__ __launch_bounds__(512, 4) void fused_iter(const float* __restrict__ x,
                                                     const float* __restrict__ w,
                                                     const float* __restrict__ vsum,  // [C][B][16]
                                                     __half* __restrict__ part,
                                                     int mode) {
    __shared__ unsigned xls[2 * 8 * XROW];       // 32 KB; dead after hoist -> red buffer
    __shared__ unsigned wls[2 * 81 * WROW];      // 40.5 KB (two subtiles, each + zero row)

    const int tid  = threadIdx.x;
    const int wave = tid >> 6;
    const int sg   = wave >> 2;          // subtile 0/1
    const int stid = tid & 255;          // id within subgroup
    const int lane = tid & 63;
    const int n    = lane & 31;
    const int g    = lane >> 5;          // k-half / o-half selector
    const int rp_m = (lane & 31) >> 4;   // r' of this lane's A row
    const int o_m  = lane & 15;          // o of this lane's A row
    const int b    = (wave & 3) * 32 + n;
    const int r0   = blockIdx.x * 16 + sg * 8;

    unsigned* const xbase = xls + sg * (8 * XROW);
    unsigned* const wbase = wls + sg * (81 * WROW);
    unsigned* const red_u = xls;         // [cp(2)][s(2)][b(128)][10] uints (fp16 x2)

    // ---- stage x subtile fp16, XOR-swizzled (r4-verified) ----
#pragma unroll
    for (int k = 0; k < 8; ++k) {
        const int f = k * 256 + stid;            // 0..2047
        const int bb = f >> 4;
        const int rr = (f >> 1) & 7;
        const int q = f & 1;
        const float4 v = *(const float4*)(x + ((size_t)bb * R_ + r0 + rr) * 8 + q * 4);
        *(uint2*)(xbase + rr * XROW + ((bb * 4 + q * 2) ^ (rr << 2))) =
            make_uint2(pk2(v.x, v.y), pk2(v.z, v.w));
    }
    // ---- stage W subtile for ALL c fp16: [c*8+r][o][4 b32] ----
#pragma unroll
    for (int k = 0; k < 5; ++k) {
        const int id = k * 256 + stid;           // 0..1279 = (c, r, o)
        const int o = id & 15;
        const int r = (id >> 4) & 7;
        const int c = id >> 7;
        const float* wp = w + ((size_t)(c * R_ + r0 + r) * 8) * 16 + o;
        const float f0 = wp[0],  f1 = wp[16],  f2 = wp[32],  f3 = wp[48];
        const float f4 = wp[64], f5 = wp[80],  f6 = wp[96],  f7 = wp[112];
        *(uint4*)(wbase + (c * 8 + r) * WROW + o * 4) =
            make_uint4(pk2(f0, f1), pk2(f2, f3), pk2(f4, f5), pk2(f6, f7));
    }
    if (stid < WROW) wbase[WZERO * WROW + stid] = 0u;
    __syncthreads();

    const int act = (g == rp_m);

    // hoisted x fragments (c-invariant); read compensates the swizzle
    half8 xbr[4];
#pragma unroll
    for (int rp = 0; rp < 4; ++rp) {
        const int row = 2 * rp + g;
        xbr[rp] = *(const half8*)(xbase + row * XROW + ((b * 4) ^ (row << 2)));
    }
    __syncthreads();    // xls reads done -> red_u aliasing is now safe

    // hoisted zero accumulator: MFMA C operand (D != C), no per-use init
    f32x16 zero16;
#pragma unroll
    for (int j = 0; j < 16; ++j) zero16[j] = 0.f;

// red write (this sg's 8-row fp16 partial) + 2-c-batch flush:
// flush sums sg0+sg1 in fp32, writes 16-row fp16 partial to part (coalesced).
#define RED_WRITE_AND_FLUSH(A0,A1,A2,A3,A4,A5,A6,A7)                           \
    {                                                                          \
        const int cp = c & 1;                                                  \
        unsigned* rw = red_u + ((cp * 2 + sg) * 128 + b) * 10;                 \
        *(uint2*)(rw + 2 * g)     = make_uint2(pk2(A0, A1), pk2(A2, A3));      \
        *(uint2*)(rw + 4 + 2 * g) = make_uint2(pk2(A4, A5), pk2(A6, A7));      \
        if (cp == 1) {                                                         \
            __syncthreads();                                                   \
            const int cp2 = tid >> 8, t2 = tid & 255;                          \
            const int b2 = t2 >> 1, oh = t2 & 1;                               \
            const int cout = c - 1 + cp2;                                      \
            const unsigned* r0p = red_u + ((cp2 * 2 + 0) * 128 + b2) * 10 + oh * 4; \
            const unsigned* r1p = red_u + ((cp2 * 2 + 1) * 128 + b2) * 10 + oh * 4; \
            const uint2 xa = *(const uint2*)r0p;                               \
            const uint2 xb2 = *(const uint2*)(r0p + 2);                        \
            const uint2 ya = *(const uint2*)r1p;                               \
            const uint2 yb = *(const uint2*)(r1p + 2);                         \
            unsigned ua[4] = {xa.x, xa.y, xb2.x, xb2.y};                       \
            unsigned ub[4] = {ya.x, ya.y, yb.x, yb.y};                         \
            unsigned uo[4];                                                    \
            _Pragma("unroll")                                                  \
            for (int j = 0; j < 4; ++j) {                                      \
                const float2 fa = __half22float2(*(const __half2*)&ua[j]);     \
                const float2 fb = __half22float2(*(const __half2*)&ub[j]);     \
                uo[j] = pk2(fa.x + fb.x, fa.y + fb.y);                         \
            }                                                                  \
            *(uint4*)(part + ((size_t)blockIdx.x * C_ + cout) * (B_ * O_)      \
                      + b2 * O_ + oh * 8) = make_uint4(uo[0], uo[1], uo[2], uo[3]); \
            __syncthreads();                                                   \
        }                                                                      \
    }

    if (mode) {
        // ================= mode 1: softmax-weighted =================
        // ---- phase 2: denominators d[r] = sum_c exp(p[c,r]) ----
        float dinv[4];
        {
            float dacc[4] = {0.f, 0.f, 0.f, 0.f};
#pragma unroll 1
            for (int c = 0; c < C_; ++c) {
                const float4* vp = (const float4*)(vsum + ((size_t)c * B_ + b) * O_ + 4 * g);
                const float4 va = vp[0];   // o = 4g..4g+3
                const float4 vb = vp[2];   // o = 8+4g..
#pragma unroll
                for (int rp = 0; rp < 4; ++rp) {
                    const int woff = act ? ((c * 8 + 2 * rp + g) * WROW + o_m * 4)
                                         : (WZERO * WROW);
                    const half8 a = *(const half8*)(wbase + woff);
                    const f32x16 u = __builtin_amdgcn_mfma_f32_32x32x16_f16(a, xbr[rp], zero16, 0, 0, 0);
                    const float p0 = u[0] * va.x + u[1] * va.y + u[2] * va.z + u[3] * va.w
                                   + u[4] * vb.x + u[5] * vb.y + u[6] * vb.z + u[7] * vb.w;
                    const float p1 = u[8] * va.x + u[9] * va.y + u[10] * va.z + u[11] * va.w
                                   + u[12] * vb.x + u[13] * vb.y + u[14] * vb.z + u[15] * vb.w;
                    const float send = g ? p0 : p1;
                    const float recv = xswap32(send);
                    const float pg = (g ? p1 : p0) + recv;
                    dacc[rp] += __expf(pg);
                }
            }
#pragma unroll
            for (int rp = 0; rp < 4; ++rp) dinv[rp] = 1.0f / dacc[rp];
        }

        // ---- phase 3: weighted accumulation (8-wide acc) ----
#pragma unroll 1
        for (int c = 0; c < C_; ++c) {
            const float4* vp = (const float4*)(vsum + ((size_t)c * B_ + b) * O_ + 4 * g);
            const float4 va = vp[0];
            const float4 vb = vp[2];
            float acc[8];
#pragma unroll
            for (int rp = 0; rp < 4; ++rp) {
                const int woff = act ? ((c * 8 + 2 * rp + g) * WROW + o_m * 4)
                                     : (WZERO * WROW);
                const half8 a = *(const half8*)(wbase + woff);
                const f32x16 u = __builtin_amdgcn_mfma_f32_32x32x16_f16(a, xbr[rp], zero16, 0, 0, 0);
                const float p0 = u[0] * va.x + u[1] * va.y + u[2] * va.z + u[3] * va.w
                               + u[4] * vb.x + u[5] * vb.y + u[6] * vb.z + u[7] * vb.w;
                const float p1 = u[8] * va.x + u[9] * va.y + u[10] * va.z + u[11] * va.w
                               + u[12] * vb.x + u[13] * vb.y + u[14] * vb.z + u[15] * vb.w;
                const float send = g ? p0 : p1;
                const float recv = xswap32(send);
                const float pg = (g ? p1 : p0) + recv;
                const float w_own = __expf(pg) * dinv[rp];     // weight for r = 2rp+g
                const float w_oth = xswap32(w_own);            // partner's (r = 2rp+(1-g))
                const float c0 = g ? w_oth : w_own;            // r' = 0 rows (u[0..7])
                const float c1 = g ? w_own : w_oth;            // r' = 1 rows (u[8..15])
                if (rp == 0) {
#pragma unroll
                    for (int j = 0; j < 8; ++j) acc[j] = c0 * u[j] + c1 * u[j + 8];
                } else {
#pragma unroll
                    for (int j = 0; j < 8; ++j) acc[j] += c0 * u[j] + c1 * u[j + 8];
                }
            }
            RED_WRITE_AND_FLUSH(acc[0], acc[1], acc[2], acc[3],
                                acc[4], acc[5], acc[6], acc[7]);
        }
    } else {
        // ================= mode 0: uniform weights 0.1 =================
#pragma unroll 1
        for (int c = 0; c < C_; ++c) {
            f32x16 acc;
#pragma unroll
            for (int rp = 0; rp < 4; ++rp) {
                const int woff = act ? ((c * 8 + 2 * rp + g) * WROW + o_m * 4)
                                     : (WZERO * WROW);
                const half8 a = *(const half8*)(wbase + woff);
                // first rp consumes zero16 directly (no acc init copies)
                acc = __builtin_amdgcn_mfma_f32_32x32x16_f16(a, xbr[rp],
                                                             rp == 0 ? zero16 : acc, 0, 0, 0);
            }
            const float f0 = (acc[0] + acc[8])  * 0.1f, f1 = (acc[1] + acc[9])  * 0.1f;
            const float f2 = (acc[2] + acc[10]) * 0.1f, f3 = (acc[3] + acc[11]) * 0.1f;
            const float f4 = (acc[4] + acc[12]) * 0.1f, f5 = (acc[5] + acc[13]) * 0.1f;
            const float f6 = (acc[6] + acc[14]) * 0.1f, f7 = (acc[7] + acc[15]) * 0.1f;
            RED_WRITE_AND_FLUSH(f0, f1, f2, f3, f4, f5, f6, f7);
        }
    }
#undef RED_WRITE_AND_FLUSH
}

// ---------------------------------------------------------------------------
// finish_fused: single-level reduction of part (512 slots) + squash.
// grid 320, block 512. Thread (q = tid>>5, pp = tid&31) sums slot range
// [q*32, q*32+32) at pair-index pi = blockIdx*32+pp. LDS tree 16 -> 1, then
// the first 32 lanes squash (8-lane shfl groups = 16 o's) and write.
// mode 0: vsum = v; 1: vsum += v; 2: out = v.
// ---------------------------------------------------------------------------
__global__ __launch_bounds__(512) void finish_fused(const __half* __restrict__ part,
                                                    float* __restrict__ vsum,   // [C][B][16]
                                                    float* __restrict__ out,    // [B][C][16]
                                                    int mode) {
    __shared__ float2 red[16][32];
    const int q  = threadIdx.x >> 5;           // slot-sixteenth 0..15
    const int pp = threadIdx.x & 31;
    const int pi = blockIdx.x * 32 + pp;       // t-pair index 0..10239

    const unsigned* pu = (const unsigned*)part + (size_t)q * 32 * (SBO / 2) + pi;
    float sx = 0.f, sy = 0.f;
#pragma unroll 8
    for (int s = 0; s < 32; ++s) {
        const unsigned uv = pu[(size_t)s * (SBO / 2)];
        const float2 f = __half22float2(*(const __half2*)&uv);
        sx += f.x; sy += f.y;
    }
    red[q][pp] = make_float2(sx, sy);
    __syncthreads();

    if (threadIdx.x < 32) {
        float2 s2 = red[0][pp];
#pragma unroll
        for (int j = 1; j < 16; ++j) { s2.x += red[j][pp].x; s2.y += red[j][pp].y; }

        float sq = s2.x * s2.x + s2.y * s2.y;
        sq += __shfl_xor(sq, 1);
        sq += __shfl_xor(sq, 2);
        sq += __shfl_xor(sq, 4);
        const float scale = sq / ((1.0f + sq) * sqrtf(sq + 1e-8f));
        const float v0 = scale * s2.x, v1 = scale * s2.y;
        const int t0 = 2 * pi;

        if (mode == 0) {
            *(float2*)(vsum + t0) = make_float2(v0, v1);
        } else if (mode == 1) {
            const float2 old = *(const float2*)(vsum + t0);
            *(float2*)(vsum + t0) = make_float2(old.x + v0, old.y + v1);
        } else {
            const int o = t0 & 15, b = (t0 >> 4) & 127, c = t0 >> 11;
            *(float2*)(out + ((size_t)b * C_ + c) * O_ + o) = make_float2(v0, v1);
        }
    }
}

extern "C" void kernel_launch(void* const* d_in, const int* in_sizes, int n_in,
                              void* d_out, int out_size, void* d_ws, size_t ws_size,
                              hipStream_t stream) {
    const float* x = (const float*)d_in[0];   // [B,R,8]
    const float* w = (const float*)d_in[1];   // [C,R,8,16]
    float* out = (float*)d_out;               // [B,C,16]

    __half* part = (__half*)d_ws;                          // 512*20480 fp16 = 21.0 MB
    float* vsum  = (float*)(part + (size_t)SLOTS * SBO);   // 20480 f ([C][B][16])

    const dim3 fgrid(R_ / 16);             // 512 blocks of 512 threads
    const dim3 ggrid(320);                 // finish_fused

    for (int it = 0; it < 3; ++it) {
        const int mode = (it > 0);
        const int fmode = (it == 2) ? 2 : it;   // finish: 0=set, 1=add, 2=out
        fused_iter<<<fgrid, 512, 0, stream>>>(x, w, vsum, part, mode);
        finish_fused<<<ggrid, 512, 0, stream>>>(part, vsum, out, fmode);
    }
}

// Round 13
// 200.573 us; speedup vs baseline: 1.0417x; 1.0417x over previous
//
#include <hip/hip_runtime.h>
#include <hip/hip_fp16.h>
#include <math.h>

#define B_ 128
#define C_ 10
#define R_ 8192
#define I_ 8
#define O_ 16

typedef __attribute__((ext_vector_type(8))) _Float16 half8;
typedef __attribute__((ext_vector_type(16))) float f32x16;

#define XROW 512           // uints per x r-row: 128 b * 4
#define WROW 64            // uints per W row: 16 o * 4
#define WZERO 80           // zero-row index (shared by both A variants)
#define SBO (C_ * B_ * O_) // 20480
#define SLOTS 512          // part slots (one per block, 16 r-rows each)

__device__ __forceinline__ unsigned pk2(float a, float b) {
    __half2 h = __floats2half2_rn(a, b);
    return *(unsigned*)&h;
}

// ---------------------------------------------------------------------------
// fused_iter: one routing iteration. grid 512, block 512 (8 waves), TR=16.
// Structure from r9/r10 (in-block LDS reduction, part = 21 MB, zero16 C-op).
// r12 lesson: kernel is VALU-ISSUE-bound (permlane's +3 VALU/swap cost ~6%
// time; bpermute latency was already wave-hidden). So r13 CUTS VALU ops:
// phase-3 weighting moved to the matrix pipe via the identity
//   s[c,o,b] = sum_{r,i} W[c,r,i,o] * (x[b,r,i] * cij[r,b])
// Second MFMA per (c,rp) with FULL A (m = o, k = (r'',i)): lanes rp_m==0 read
// the SAME wls slot as the block-diag A; rp_m==1 lanes read the zero row --
// no new staging. Each lane scales its x k-half (r''=g) by ITS OWN weight
// (4 v_pk_mul_f16), so the partner-weight swap vanishes. Removes 640 weight
// FMAs + 40 bpermutes per wave; adds 40 MFMA + ~360 cheap pk/cvt ops.
// D rows of the full-A MFMA (regs 0-7) land exactly on the o-groups the
// flush writes (4g.. / 8+4g..). fp16 x*c rounding: absmax pred <= 0.008.
// Spill tripwire: WRITE_SIZE must stay 20480 KB exactly.
// ---------------------------------------------------------------------------
__global__ __launch_bounds__(512, 4) void fused_iter(const float* __restrict__ x,
                                                     const float* __restrict__ w,
                                                     const float* __restrict__ vsum,  // [C][B][16]
                                                     __half* __restrict__ part,
                                                     int mode) {
    __shared__ unsigned xls[2 * 8 * XROW];       // 32 KB; dead after hoist -> red buffer
    __shared__ unsigned wls[2 * 81 * WROW];      // 40.5 KB (two subtiles, each + zero row)

    const int tid  = threadIdx.x;
    const int wave = tid >> 6;
    const int sg   = wave >> 2;          // subtile 0/1
    const int stid = tid & 255;          // id within subgroup
    const int lane = tid & 63;
    const int n    = lane & 31;
    const int g    = lane >> 5;          // k-half / o-half selector
    const int rp_m = (lane & 31) >> 4;   // r' of this lane's A row (block-diag)
    const int o_m  = lane & 15;          // o of this lane's A row
    const int b    = (wave & 3) * 32 + n;
    const int r0   = blockIdx.x * 16 + sg * 8;

    unsigned* const xbase = xls + sg * (8 * XROW);
    unsigned* const wbase = wls + sg * (81 * WROW);
    unsigned* const red_u = xls;         // [cp(2)][s(2)][b(128)][10] uints (fp16 x2)

    // ---- stage x subtile fp16, XOR-swizzled (r4-verified) ----
#pragma unroll
    for (int k = 0; k < 8; ++k) {
        const int f = k * 256 + stid;            // 0..2047
        const int bb = f >> 4;
        const int rr = (f >> 1) & 7;
        const int q = f & 1;
        const float4 v = *(const float4*)(x + ((size_t)bb * R_ + r0 + rr) * 8 + q * 4);
        *(uint2*)(xbase + rr * XROW + ((bb * 4 + q * 2) ^ (rr << 2))) =
            make_uint2(pk2(v.x, v.y), pk2(v.z, v.w));
    }
    // ---- stage W subtile for ALL c fp16: [c*8+r][o][4 b32] ----
#pragma unroll
    for (int k = 0; k < 5; ++k) {
        const int id = k * 256 + stid;           // 0..1279 = (c, r, o)
        const int o = id & 15;
        const int r = (id >> 4) & 7;
        const int c = id >> 7;
        const float* wp = w + ((size_t)(c * R_ + r0 + r) * 8) * 16 + o;
        const float f0 = wp[0],  f1 = wp[16],  f2 = wp[32],  f3 = wp[48];
        const float f4 = wp[64], f5 = wp[80],  f6 = wp[96],  f7 = wp[112];
        *(uint4*)(wbase + (c * 8 + r) * WROW + o * 4) =
            make_uint4(pk2(f0, f1), pk2(f2, f3), pk2(f4, f5), pk2(f6, f7));
    }
    if (stid < WROW) wbase[WZERO * WROW + stid] = 0u;
    __syncthreads();

    const int act = (g == rp_m);         // block-diag A activity
    const int actf = (rp_m == 0);        // full-A activity (rows m = o < 16)

    // hoisted x fragments (c-invariant); read compensates the swizzle
    half8 xbr[4];
#pragma unroll
    for (int rp = 0; rp < 4; ++rp) {
        const int row = 2 * rp + g;
        xbr[rp] = *(const half8*)(xbase + row * XROW + ((b * 4) ^ (row << 2)));
    }
    __syncthreads();    // xls reads done -> red_u aliasing is now safe

    // hoisted zero accumulator: MFMA C operand (D != C), no per-use init
    f32x16 zero16;
#pragma unroll
    for (int j = 0; j < 16; ++j) zero16[j] = 0.f;

// red write (this sg's 8-row fp16 partial) + 2-c-batch flush:
// flush sums sg0+sg1 in fp32, writes 16-row fp16 partial to part (coalesced).
#define RED_WRITE_AND_FLUSH(A0,A1,A2,A3,A4,A5,A6,A7)                           \
    {                                                                          \
        const int cp = c & 1;                                                  \
        unsigned* rw = red_u + ((cp * 2 + sg) * 128 + b) * 10;                 \
        *(uint2*)(rw + 2 * g)     = make_uint2(pk2(A0, A1), pk2(A2, A3));      \
        *(uint2*)(rw + 4 + 2 * g) = make_uint2(pk2(A4, A5), pk2(A6, A7));      \
        if (cp == 1) {                                                         \
            __syncthreads();                                                   \
            const int cp2 = tid >> 8, t2 = tid & 255;                          \
            const int b2 = t2 >> 1, oh = t2 & 1;                               \
            const int cout = c - 1 + cp2;                                      \
            const unsigned* r0p = red_u + ((cp2 * 2 + 0) * 128 + b2) * 10 + oh * 4; \
            const unsigned* r1p = red_u + ((cp2 * 2 + 1) * 128 + b2) * 10 + oh * 4; \
            const uint2 xa = *(const uint2*)r0p;                               \
            const uint2 xb2 = *(const uint2*)(r0p + 2);                        \
            const uint2 ya = *(const uint2*)r1p;                               \
            const uint2 yb = *(const uint2*)(r1p + 2);                         \
            unsigned ua[4] = {xa.x, xa.y, xb2.x, xb2.y};                       \
            unsigned ub[4] = {ya.x, ya.y, yb.x, yb.y};                         \
            unsigned uo[4];                                                    \
            _Pragma("unroll")                                                  \
            for (int j = 0; j < 4; ++j) {                                      \
                const float2 fa = __half22float2(*(const __half2*)&ua[j]);     \
                const float2 fb = __half22float2(*(const __half2*)&ub[j]);     \
                uo[j] = pk2(fa.x + fb.x, fa.y + fb.y);                         \
            }                                                                  \
            *(uint4*)(part + ((size_t)blockIdx.x * C_ + cout) * (B_ * O_)      \
                      + b2 * O_ + oh * 8) = make_uint4(uo[0], uo[1], uo[2], uo[3]); \
            __syncthreads();                                                   \
        }                                                                      \
    }

    if (mode) {
        // ================= mode 1: softmax-weighted =================
        // ---- phase 2: denominators d[r] = sum_c exp(p[c,r]) ----
        float dinv[4];
        {
            float dacc[4] = {0.f, 0.f, 0.f, 0.f};
#pragma unroll 1
            for (int c = 0; c < C_; ++c) {
                const float4* vp = (const float4*)(vsum + ((size_t)c * B_ + b) * O_ + 4 * g);
                const float4 va = vp[0];   // o = 4g..4g+3
                const float4 vb = vp[2];   // o = 8+4g..
#pragma unroll
                for (int rp = 0; rp < 4; ++rp) {
                    const int woff = act ? ((c * 8 + 2 * rp + g) * WROW + o_m * 4)
                                         : (WZERO * WROW);
                    const half8 a = *(const half8*)(wbase + woff);
                    const f32x16 u = __builtin_amdgcn_mfma_f32_32x32x16_f16(a, xbr[rp], zero16, 0, 0, 0);
                    const float p0 = u[0] * va.x + u[1] * va.y + u[2] * va.z + u[3] * va.w
                                   + u[4] * vb.x + u[5] * vb.y + u[6] * vb.z + u[7] * vb.w;
                    const float p1 = u[8] * va.x + u[9] * va.y + u[10] * va.z + u[11] * va.w
                                   + u[12] * vb.x + u[13] * vb.y + u[14] * vb.z + u[15] * vb.w;
                    const float send = g ? p0 : p1;
                    const float recv = __shfl_xor(send, 32);
                    const float pg = (g ? p1 : p0) + recv;
                    dacc[rp] += __expf(pg);
                }
            }
#pragma unroll
            for (int rp = 0; rp < 4; ++rp) dinv[rp] = 1.0f / dacc[rp];
        }

        // ---- phase 3: weighted accumulation via full-A MFMA ----
#pragma unroll 1
        for (int c = 0; c < C_; ++c) {
            const float4* vp = (const float4*)(vsum + ((size_t)c * B_ + b) * O_ + 4 * g);
            const float4 va = vp[0];
            const float4 vb = vp[2];
            f32x16 sacc;
#pragma unroll
            for (int rp = 0; rp < 4; ++rp) {
                const int wslot = (c * 8 + 2 * rp + g) * WROW + o_m * 4;
                const int woff_d = act ? wslot : (WZERO * WROW);
                const half8 ad = *(const half8*)(wbase + woff_d);
                const f32x16 u = __builtin_amdgcn_mfma_f32_32x32x16_f16(ad, xbr[rp], zero16, 0, 0, 0);
                const float p0 = u[0] * va.x + u[1] * va.y + u[2] * va.z + u[3] * va.w
                               + u[4] * vb.x + u[5] * vb.y + u[6] * vb.z + u[7] * vb.w;
                const float p1 = u[8] * va.x + u[9] * va.y + u[10] * va.z + u[11] * va.w
                               + u[12] * vb.x + u[13] * vb.y + u[14] * vb.z + u[15] * vb.w;
                const float send = g ? p0 : p1;
                const float recv = __shfl_xor(send, 32);
                const float pg = (g ? p1 : p0) + recv;
                const float w_own = __expf(pg) * dinv[rp];   // cij for r = 2rp+g (this lane's k-half)
                // scale x k-half by own weight in fp16 (v_pk_mul_f16 x4)
                const _Float16 wh = (_Float16)w_own;
                half8 xc;
#pragma unroll
                for (int j = 0; j < 8; ++j) xc[j] = (_Float16)(xbr[rp][j] * wh);
                const int woff_f = actf ? wslot : (WZERO * WROW);
                const half8 af = *(const half8*)(wbase + woff_f);
                sacc = __builtin_amdgcn_mfma_f32_32x32x16_f16(af, xc,
                                                              rp == 0 ? zero16 : sacc, 0, 0, 0);
            }
            RED_WRITE_AND_FLUSH(sacc[0], sacc[1], sacc[2], sacc[3],
                                sacc[4], sacc[5], sacc[6], sacc[7]);
        }
    } else {
        // ================= mode 0: uniform weights 0.1 (full-A, no r-fold) =====
#pragma unroll 1
        for (int c = 0; c < C_; ++c) {
            f32x16 acc;
#pragma unroll
            for (int rp = 0; rp < 4; ++rp) {
                const int woff_f = actf ? ((c * 8 + 2 * rp + g) * WROW + o_m * 4)
                                        : (WZERO * WROW);
                const half8 af = *(const half8*)(wbase + woff_f);
                acc = __builtin_amdgcn_mfma_f32_32x32x16_f16(af, xbr[rp],
                                                             rp == 0 ? zero16 : acc, 0, 0, 0);
            }
            const float f0 = acc[0] * 0.1f, f1 = acc[1] * 0.1f;
            const float f2 = acc[2] * 0.1f, f3 = acc[3] * 0.1f;
            const float f4 = acc[4] * 0.1f, f5 = acc[5] * 0.1f;
            const float f6 = acc[6] * 0.1f, f7 = acc[7] * 0.1f;
            RED_WRITE_AND_FLUSH(f0, f1, f2, f3, f4, f5, f6, f7);
        }
    }
#undef RED_WRITE_AND_FLUSH
}

// ---------------------------------------------------------------------------
// finish_fused: single-level reduction of part (512 slots) + squash.
// grid 320, block 512. Thread (q = tid>>5, pp = tid&31) sums slot range
// [q*32, q*32+32) at pair-index pi = blockIdx*32+pp. LDS tree 16 -> 1, then
// the first 32 lanes squash (8-lane shfl groups = 16 o's) and write.
// mode 0: vsum = v; 1: vsum += v; 2: out = v.
// ---------------------------------------------------------------------------
__global__ __launch_bounds__(512) void finish_fused(const __half* __restrict__ part,
                                                    float* __restrict__ vsum,   // [C][B][16]
                                                    float* __restrict__ out,    // [B][C][16]
                                                    int mode) {
    __shared__ float2 red[16][32];
    const int q  = threadIdx.x >> 5;           // slot-sixteenth 0..15
    const int pp = threadIdx.x & 31;
    const int pi = blockIdx.x * 32 + pp;       // t-pair index 0..10239

    const unsigned* pu = (const unsigned*)part + (size_t)q * 32 * (SBO / 2) + pi;
    float sx = 0.f, sy = 0.f;
#pragma unroll 8
    for (int s = 0; s < 32; ++s) {
        const unsigned uv = pu[(size_t)s * (SBO / 2)];
        const float2 f = __half22float2(*(const __half2*)&uv);
        sx += f.x; sy += f.y;
    }
    red[q][pp] = make_float2(sx, sy);
    __syncthreads();

    if (threadIdx.x < 32) {
        float2 s2 = red[0][pp];
#pragma unroll
        for (int j = 1; j < 16; ++j) { s2.x += red[j][pp].x; s2.y += red[j][pp].y; }

        float sq = s2.x * s2.x + s2.y * s2.y;
        sq += __shfl_xor(sq, 1);
        sq += __shfl_xor(sq, 2);
        sq += __shfl_xor(sq, 4);
        const float scale = sq / ((1.0f + sq) * sqrtf(sq + 1e-8f));
        const float v0 = scale * s2.x, v1 = scale * s2.y;
        const int t0 = 2 * pi;

        if (mode == 0) {
            *(float2*)(vsum + t0) = make_float2(v0, v1);
        } else if (mode == 1) {
            const float2 old = *(const float2*)(vsum + t0);
            *(float2*)(vsum + t0) = make_float2(old.x + v0, old.y + v1);
        } else {
            const int o = t0 & 15, b = (t0 >> 4) & 127, c = t0 >> 11;
            *(float2*)(out + ((size_t)b * C_ + c) * O_ + o) = make_float2(v0, v1);
        }
    }
}

extern "C" void kernel_launch(void* const* d_in, const int* in_sizes, int n_in,
                              void* d_out, int out_size, void* d_ws, size_t ws_size,
                              hipStream_t stream) {
    const float* x = (const float*)d_in[0];   // [B,R,8]
    const float* w = (const float*)d_in[1];   // [C,R,8,16]
    float* out = (float*)d_out;               // [B,C,16]

    __half* part = (__half*)d_ws;                          // 512*20480 fp16 = 21.0 MB
    float* vsum  = (float*)(part + (size_t)SLOTS * SBO);   // 20480 f ([C][B][16])

    const dim3 fgrid(R_ / 16);             // 512 blocks of 512 threads
    const dim3 ggrid(320);                 // finish_fused

    for (int it = 0; it < 3; ++it) {
        const int mode = (it > 0);
        const int fmode = (it == 2) ? 2 : it;   // finish: 0=set, 1=add, 2=out
        fused_iter<<<fgrid, 512, 0, stream>>>(x, w, vsum, part, mode);
        finish_fused<<<ggrid, 512, 0, stream>>>(part, vsum, out, fmode);
    }
}

// Round 14
// 192.789 us; speedup vs baseline: 1.0838x; 1.0404x over previous
//
#include <hip/hip_runtime.h>
#include <hip/hip_fp16.h>
#include <math.h>

#define B_ 128
#define C_ 10
#define R_ 8192
#define I_ 8
#define O_ 16

typedef __attribute__((ext_vector_type(8))) _Float16 half8;
typedef __attribute__((ext_vector_type(16))) float f32x16;

#define XROW 512           // uints per x r-row: 128 b * 4
#define WROW 64            // uints per W row: 16 o * 4
#define WZERO 80           // zero-row index (shared by both A variants)
#define SBO (C_ * B_ * O_) // 20480
#define SLOTS 512          // part slots (one per block, 16 r-rows each)

__device__ __forceinline__ unsigned pk2(float a, float b) {
    __half2 h = __floats2half2_rn(a, b);
    return *(unsigned*)&h;
}

// dot of u-half with (va,vb) as TWO independent 4-chains (ILP 4 with p0/p1):
// at 4 waves/SIMD the serial 8-chain left FMA latency uncovered (r12/r13
// effective ~5 cyc/inst). fp32 reassociation only (~ulp; fp16 dominates).
#define DOT8(U, base, va, vb)                                                  \
    ((U[base + 0] * va.x + U[base + 2] * va.z + U[base + 4] * vb.x + U[base + 6] * vb.z) + \
     (U[base + 1] * va.y + U[base + 3] * va.w + U[base + 5] * vb.y + U[base + 7] * vb.w))

// ---------------------------------------------------------------------------
// fused_iter: one routing iteration. grid 512, block 512 (8 waves), TR=16.
// Structure from r9/r10/r13 (in-block LDS reduction, part = 21 MB, zero16
// C-op, phase-3 weighting on the matrix pipe via full-A MFMA with x*cij).
// r14 change: dot reassociation (DOT8 above) in both phases.
// Spill tripwire: WRITE_SIZE must stay 20480 KB exactly.
// ---------------------------------------------------------------------------
__global__ __launch_bounds__(512, 4) void fused_iter(const float* __restrict__ x,
                                                     const float* __restrict__ w,
                                                     const float* __restrict__ vsum,  // [C][B][16]
                                                     __half* __restrict__ part,
                                                     int mode) {
    __shared__ unsigned xls[2 * 8 * XROW];       // 32 KB; dead after hoist -> red buffer
    __shared__ unsigned wls[2 * 81 * WROW];      // 40.5 KB (two subtiles, each + zero row)

    const int tid  = threadIdx.x;
    const int wave = tid >> 6;
    const int sg   = wave >> 2;          // subtile 0/1
    const int stid = tid & 255;          // id within subgroup
    const int lane = tid & 63;
    const int n    = lane & 31;
    const int g    = lane >> 5;          // k-half / o-half selector
    const int rp_m = (lane & 31) >> 4;   // r' of this lane's A row (block-diag)
    const int o_m  = lane & 15;          // o of this lane's A row
    const int b    = (wave & 3) * 32 + n;
    const int r0   = blockIdx.x * 16 + sg * 8;

    unsigned* const xbase = xls + sg * (8 * XROW);
    unsigned* const wbase = wls + sg * (81 * WROW);
    unsigned* const red_u = xls;         // [cp(2)][s(2)][b(128)][10] uints (fp16 x2)

    // ---- stage x subtile fp16, XOR-swizzled (r4-verified) ----
#pragma unroll
    for (int k = 0; k < 8; ++k) {
        const int f = k * 256 + stid;            // 0..2047
        const int bb = f >> 4;
        const int rr = (f >> 1) & 7;
        const int q = f & 1;
        const float4 v = *(const float4*)(x + ((size_t)bb * R_ + r0 + rr) * 8 + q * 4);
        *(uint2*)(xbase + rr * XROW + ((bb * 4 + q * 2) ^ (rr << 2))) =
            make_uint2(pk2(v.x, v.y), pk2(v.z, v.w));
    }
    // ---- stage W subtile for ALL c fp16: [c*8+r][o][4 b32] ----
#pragma unroll
    for (int k = 0; k < 5; ++k) {
        const int id = k * 256 + stid;           // 0..1279 = (c, r, o)
        const int o = id & 15;
        const int r = (id >> 4) & 7;
        const int c = id >> 7;
        const float* wp = w + ((size_t)(c * R_ + r0 + r) * 8) * 16 + o;
        const float f0 = wp[0],  f1 = wp[16],  f2 = wp[32],  f3 = wp[48];
        const float f4 = wp[64], f5 = wp[80],  f6 = wp[96],  f7 = wp[112];
        *(uint4*)(wbase + (c * 8 + r) * WROW + o * 4) =
            make_uint4(pk2(f0, f1), pk2(f2, f3), pk2(f4, f5), pk2(f6, f7));
    }
    if (stid < WROW) wbase[WZERO * WROW + stid] = 0u;
    __syncthreads();

    const int act = (g == rp_m);         // block-diag A activity
    const int actf = (rp_m == 0);        // full-A activity (rows m = o < 16)

    // hoisted x fragments (c-invariant); read compensates the swizzle
    half8 xbr[4];
#pragma unroll
    for (int rp = 0; rp < 4; ++rp) {
        const int row = 2 * rp + g;
        xbr[rp] = *(const half8*)(xbase + row * XROW + ((b * 4) ^ (row << 2)));
    }
    __syncthreads();    // xls reads done -> red_u aliasing is now safe

    // hoisted zero accumulator: MFMA C operand (D != C), no per-use init
    f32x16 zero16;
#pragma unroll
    for (int j = 0; j < 16; ++j) zero16[j] = 0.f;

// red write (this sg's 8-row fp16 partial) + 2-c-batch flush:
// flush sums sg0+sg1 in fp32, writes 16-row fp16 partial to part (coalesced).
#define RED_WRITE_AND_FLUSH(A0,A1,A2,A3,A4,A5,A6,A7)                           \
    {                                                                          \
        const int cp = c & 1;                                                  \
        unsigned* rw = red_u + ((cp * 2 + sg) * 128 + b) * 10;                 \
        *(uint2*)(rw + 2 * g)     = make_uint2(pk2(A0, A1), pk2(A2, A3));      \
        *(uint2*)(rw + 4 + 2 * g) = make_uint2(pk2(A4, A5), pk2(A6, A7));      \
        if (cp == 1) {                                                         \
            __syncthreads();                                                   \
            const int cp2 = tid >> 8, t2 = tid & 255;                          \
            const int b2 = t2 >> 1, oh = t2 & 1;                               \
            const int cout = c - 1 + cp2;                                      \
            const unsigned* r0p = red_u + ((cp2 * 2 + 0) * 128 + b2) * 10 + oh * 4; \
            const unsigned* r1p = red_u + ((cp2 * 2 + 1) * 128 + b2) * 10 + oh * 4; \
            const uint2 xa = *(const uint2*)r0p;                               \
            const uint2 xb2 = *(const uint2*)(r0p + 2);                        \
            const uint2 ya = *(const uint2*)r1p;                               \
            const uint2 yb = *(const uint2*)(r1p + 2);                         \
            unsigned ua[4] = {xa.x, xa.y, xb2.x, xb2.y};                       \
            unsigned ub[4] = {ya.x, ya.y, yb.x, yb.y};                         \
            unsigned uo[4];                                                    \
            _Pragma("unroll")                                                  \
            for (int j = 0; j < 4; ++j) {                                      \
                const float2 fa = __half22float2(*(const __half2*)&ua[j]);     \
                const float2 fb = __half22float2(*(const __half2*)&ub[j]);     \
                uo[j] = pk2(fa.x + fb.x, fa.y + fb.y);                         \
            }                                                                  \
            *(uint4*)(part + ((size_t)blockIdx.x * C_ + cout) * (B_ * O_)      \
                      + b2 * O_ + oh * 8) = make_uint4(uo[0], uo[1], uo[2], uo[3]); \
            __syncthreads();                                                   \
        }                                                                      \
    }

    if (mode) {
        // ================= mode 1: softmax-weighted =================
        // ---- phase 2: denominators d[r] = sum_c exp(p[c,r]) ----
        float dinv[4];
        {
            float dacc[4] = {0.f, 0.f, 0.f, 0.f};
#pragma unroll 1
            for (int c = 0; c < C_; ++c) {
                const float4* vp = (const float4*)(vsum + ((size_t)c * B_ + b) * O_ + 4 * g);
                const float4 va = vp[0];   // o = 4g..4g+3
                const float4 vb = vp[2];   // o = 8+4g..
#pragma unroll
                for (int rp = 0; rp < 4; ++rp) {
                    const int woff = act ? ((c * 8 + 2 * rp + g) * WROW + o_m * 4)
                                         : (WZERO * WROW);
                    const half8 a = *(const half8*)(wbase + woff);
                    const f32x16 u = __builtin_amdgcn_mfma_f32_32x32x16_f16(a, xbr[rp], zero16, 0, 0, 0);
                    const float p0 = DOT8(u, 0, va, vb);
                    const float p1 = DOT8(u, 8, va, vb);
                    const float send = g ? p0 : p1;
                    const float recv = __shfl_xor(send, 32);
                    const float pg = (g ? p1 : p0) + recv;
                    dacc[rp] += __expf(pg);
                }
            }
#pragma unroll
            for (int rp = 0; rp < 4; ++rp) dinv[rp] = 1.0f / dacc[rp];
        }

        // ---- phase 3: weighted accumulation via full-A MFMA ----
#pragma unroll 1
        for (int c = 0; c < C_; ++c) {
            const float4* vp = (const float4*)(vsum + ((size_t)c * B_ + b) * O_ + 4 * g);
            const float4 va = vp[0];
            const float4 vb = vp[2];
            f32x16 sacc;
#pragma unroll
            for (int rp = 0; rp < 4; ++rp) {
                const int wslot = (c * 8 + 2 * rp + g) * WROW + o_m * 4;
                const int woff_d = act ? wslot : (WZERO * WROW);
                const half8 ad = *(const half8*)(wbase + woff_d);
                const f32x16 u = __builtin_amdgcn_mfma_f32_32x32x16_f16(ad, xbr[rp], zero16, 0, 0, 0);
                const float p0 = DOT8(u, 0, va, vb);
                const float p1 = DOT8(u, 8, va, vb);
                const float send = g ? p0 : p1;
                const float recv = __shfl_xor(send, 32);
                const float pg = (g ? p1 : p0) + recv;
                const float w_own = __expf(pg) * dinv[rp];   // cij for r = 2rp+g
                const _Float16 wh = (_Float16)w_own;
                half8 xc;
#pragma unroll
                for (int j = 0; j < 8; ++j) xc[j] = (_Float16)(xbr[rp][j] * wh);
                const int woff_f = actf ? wslot : (WZERO * WROW);
                const half8 af = *(const half8*)(wbase + woff_f);
                sacc = __builtin_amdgcn_mfma_f32_32x32x16_f16(af, xc,
                                                              rp == 0 ? zero16 : sacc, 0, 0, 0);
            }
            RED_WRITE_AND_FLUSH(sacc[0], sacc[1], sacc[2], sacc[3],
                                sacc[4], sacc[5], sacc[6], sacc[7]);
        }
    } else {
        // ================= mode 0: uniform weights 0.1 (full-A, no r-fold) =====
#pragma unroll 1
        for (int c = 0; c < C_; ++c) {
            f32x16 acc;
#pragma unroll
            for (int rp = 0; rp < 4; ++rp) {
                const int woff_f = actf ? ((c * 8 + 2 * rp + g) * WROW + o_m * 4)
                                        : (WZERO * WROW);
                const half8 af = *(const half8*)(wbase + woff_f);
                acc = __builtin_amdgcn_mfma_f32_32x32x16_f16(af, xbr[rp],
                                                             rp == 0 ? zero16 : acc, 0, 0, 0);
            }
            const float f0 = acc[0] * 0.1f, f1 = acc[1] * 0.1f;
            const float f2 = acc[2] * 0.1f, f3 = acc[3] * 0.1f;
            const float f4 = acc[4] * 0.1f, f5 = acc[5] * 0.1f;
            const float f6 = acc[6] * 0.1f, f7 = acc[7] * 0.1f;
            RED_WRITE_AND_FLUSH(f0, f1, f2, f3, f4, f5, f6, f7);
        }
    }
#undef RED_WRITE_AND_FLUSH
}

// ---------------------------------------------------------------------------
// finish_fused (r14 rewrite): vectorized uint4 loads (16 B/lane; was scalar
// 4 B -- G13). grid 80, block 512. part as uint4 columns: 2560 cols/slot.
// Block owns 32 cols; thread (jj = tid&31, sgp = tid>>5) sums 32 slots of
// col blockIdx*32+jj (half-wave reads 512 B contiguous per slot). LDS tree
// red[16][32][9] (pad 9 breaks the 8-way bank conflict on the e-stride),
// then lanes 0..255 own one (col, elem) each: 16-lane groups = one (c,b)'s
// 16 o's -> shfl squash, coalesced write.
// mode 0: vsum = v; 1: vsum += v; 2: out = v.
// ---------------------------------------------------------------------------
__global__ __launch_bounds__(512) void finish_fused(const __half* __restrict__ part,
                                                    float* __restrict__ vsum,   // [C][B][16]
                                                    float* __restrict__ out,    // [B][C][16]
                                                    int mode) {
    __shared__ float red[16][32][9];
    const int jj  = threadIdx.x & 31;
    const int sgp = threadIdx.x >> 5;          // slot-sixteenth 0..15
    const size_t col = (size_t)blockIdx.x * 32 + jj;   // uint4-column 0..2559

    const uint4* pu = (const uint4*)part + (size_t)(sgp * 32) * (SBO / 8) + col;
    float s[8];
#pragma unroll
    for (int e = 0; e < 8; ++e) s[e] = 0.f;
#pragma unroll 8
    for (int ss = 0; ss < 32; ++ss) {
        const uint4 v = pu[(size_t)ss * (SBO / 8)];
        const float2 f0 = __half22float2(*(const __half2*)&v.x);
        const float2 f1 = __half22float2(*(const __half2*)&v.y);
        const float2 f2 = __half22float2(*(const __half2*)&v.z);
        const float2 f3 = __half22float2(*(const __half2*)&v.w);
        s[0] += f0.x; s[1] += f0.y; s[2] += f1.x; s[3] += f1.y;
        s[4] += f2.x; s[5] += f2.y; s[6] += f3.x; s[7] += f3.y;
    }
#pragma unroll
    for (int e = 0; e < 8; ++e) red[sgp][jj][e] = s[e];
    __syncthreads();

    if (threadIdx.x < 256) {
        const int j2 = threadIdx.x >> 3;       // col within block 0..31
        const int e  = threadIdx.x & 7;
        float sum = red[0][j2][e];
#pragma unroll
        for (int k = 1; k < 16; ++k) sum += red[k][j2][e];

        float sq = sum * sum;
        sq += __shfl_xor(sq, 1);
        sq += __shfl_xor(sq, 2);
        sq += __shfl_xor(sq, 4);
        sq += __shfl_xor(sq, 8);
        const float scale = sq / ((1.0f + sq) * sqrtf(sq + 1e-8f));
        const float v = scale * sum;
        const size_t h = ((size_t)blockIdx.x * 32 + j2) * 8 + e;   // index in [C][B][16]

        if (mode == 0) {
            vsum[h] = v;
        } else if (mode == 1) {
            vsum[h] += v;
        } else {
            const int o = (int)(h & 15), b = (int)((h >> 4) & 127), c = (int)(h >> 11);
            out[((size_t)b * C_ + c) * O_ + o] = v;
        }
    }
}

extern "C" void kernel_launch(void* const* d_in, const int* in_sizes, int n_in,
                              void* d_out, int out_size, void* d_ws, size_t ws_size,
                              hipStream_t stream) {
    const float* x = (const float*)d_in[0];   // [B,R,8]
    const float* w = (const float*)d_in[1];   // [C,R,8,16]
    float* out = (float*)d_out;               // [B,C,16]

    __half* part = (__half*)d_ws;                          // 512*20480 fp16 = 21.0 MB
    float* vsum  = (float*)(part + (size_t)SLOTS * SBO);   // 20480 f ([C][B][16])

    const dim3 fgrid(R_ / 16);             // 512 blocks of 512 threads
    const dim3 ggrid(80);                  // finish_fused (32 uint4-cols each)

    for (int it = 0; it < 3; ++it) {
        const int mode = (it > 0);
        const int fmode = (it == 2) ? 2 : it;   // finish: 0=set, 1=add, 2=out
        fused_iter<<<fgrid, 512, 0, stream>>>(x, w, vsum, part, mode);
        finish_fused<<<ggrid, 512, 0, stream>>>(part, vsum, out, fmode);
    }
}